// Round 1
// baseline (36.876 us; speedup 1.0000x reference)
//
#include <hip/hip_runtime.h>

static constexpr int kNodes = 100000;
static constexpr int kEdges = 1600000;
static constexpr int kD     = 128;

// ---------------------------------------------------------------------------
// Detect whether edge_index arrived as int64 (high 32 bits of every entry are
// zero, since indices < 100000) or as int32 (pairs of indices packed, high
// word almost surely nonzero). Deterministic for fixed inputs.
// ---------------------------------------------------------------------------
__global__ __launch_bounds__(64) void detect_idx(const unsigned long long* __restrict__ ei,
                                                 int* __restrict__ flag) {
    if (threadIdx.x == 0 && blockIdx.x == 0) {
        unsigned long long orr = 0ull;
        for (int i = 0; i < 256; ++i) orr |= (ei[i] >> 32);
        *flag = (orr == 0ull) ? 1 : 0;   // 1 => int64 layout
    }
}

// ---------------------------------------------------------------------------
// Phase 1: per-node partial dot products.
// h[n] = { emb[n]·W[0][0:128], emb[n]·W[1][0:128],
//          emb[n]·W[0][128:256], emb[n]·W[1][128:256] }
// 16 lanes per node, 8 columns per lane, W slices in registers.
// ---------------------------------------------------------------------------
__global__ __launch_bounds__(256) void node_pre(const float* __restrict__ emb,
                                                const float* __restrict__ W,
                                                float* __restrict__ h) {
    const int lane16 = threadIdx.x & 15;
    const int c0 = lane16 * 8;

    float w0[8], w1[8], w2[8], w3[8];
#pragma unroll
    for (int k = 0; k < 8; ++k) {
        w0[k] = W[c0 + k];            // W[0][c0+k]
        w1[k] = W[256 + c0 + k];      // W[1][c0+k]
        w2[k] = W[128 + c0 + k];      // W[0][128+c0+k]
        w3[k] = W[384 + c0 + k];      // W[1][128+c0+k]
    }

    const int group   = (blockIdx.x * blockDim.x + threadIdx.x) >> 4;
    const int ngroups = (gridDim.x * blockDim.x) >> 4;

    for (int n = group; n < kNodes; n += ngroups) {
        const float4* row = (const float4*)(emb + (size_t)n * kD + c0);
        float4 ea = row[0];
        float4 eb = row[1];
        float e[8] = {ea.x, ea.y, ea.z, ea.w, eb.x, eb.y, eb.z, eb.w};
        float p0 = 0.f, p1 = 0.f, p2 = 0.f, p3 = 0.f;
#pragma unroll
        for (int k = 0; k < 8; ++k) {
            p0 += e[k] * w0[k];
            p1 += e[k] * w1[k];
            p2 += e[k] * w2[k];
            p3 += e[k] * w3[k];
        }
        // reduce across the 16-lane group (xor masks 1,2,4,8 stay in-group)
#pragma unroll
        for (int m = 1; m < 16; m <<= 1) {
            p0 += __shfl_xor(p0, m, 64);
            p1 += __shfl_xor(p1, m, 64);
            p2 += __shfl_xor(p2, m, 64);
            p3 += __shfl_xor(p3, m, 64);
        }
        if (lane16 == 0) {
            ((float4*)h)[n] = make_float4(p0, p1, p2, p3);
        }
    }
}

// ---------------------------------------------------------------------------
// Phase 2: one thread per edge. Gather two 16B h-entries (1.6 MB table,
// L2-resident), add bias, 2-way softmax, write float2.
// ---------------------------------------------------------------------------
__global__ __launch_bounds__(256) void edge_attn(const void* __restrict__ eiv,
                                                 const float* __restrict__ h,
                                                 const float* __restrict__ b,
                                                 const int* __restrict__ flag,
                                                 float* __restrict__ out) {
    const int e = blockIdx.x * blockDim.x + threadIdx.x;
    if (e >= kEdges) return;

    int r, c;
    if (*flag) {   // uniform branch
        const long long* ei = (const long long*)eiv;
        r = (int)ei[e];
        c = (int)ei[kEdges + e];
    } else {
        const int* ei = (const int*)eiv;
        r = ei[e];
        c = ei[kEdges + e];
    }

    float4 hr = ((const float4*)h)[r];
    float4 hc = ((const float4*)h)[c];

    const float b0 = b[0], b1 = b[1];
    float s0 = hr.x + hc.z + b0;
    float s1 = hr.y + hc.w + b1;
    float m  = fmaxf(s0, s1);
    float x0 = __expf(s0 - m);
    float x1 = __expf(s1 - m);
    float inv = 1.0f / (x0 + x1);
    ((float2*)out)[e] = make_float2(x0 * inv, x1 * inv);
}

extern "C" void kernel_launch(void* const* d_in, const int* in_sizes, int n_in,
                              void* d_out, int out_size, void* d_ws, size_t ws_size,
                              hipStream_t stream) {
    const float* emb = (const float*)d_in[0];
    const void*  ei  = d_in[1];
    const float* W   = (const float*)d_in[2];
    const float* b   = (const float*)d_in[3];
    float* out = (float*)d_out;

    int*   flag = (int*)d_ws;                       // 4 bytes
    float* h    = (float*)((char*)d_ws + 256);      // 1.6 MB, 16B-aligned

    detect_idx<<<1, 64, 0, stream>>>((const unsigned long long*)ei, flag);

    // 16 lanes per node -> kNodes*16 threads
    node_pre<<<(kNodes * 16 + 255) / 256, 256, 0, stream>>>(emb, W, h);

    edge_attn<<<(kEdges + 255) / 256, 256, 0, stream>>>(ei, h, b, flag, out);
}

// Round 2
// 32.760 us; speedup vs baseline: 1.1256x; 1.1256x over previous
//
#include <hip/hip_runtime.h>

static constexpr int kNodes = 100000;
static constexpr int kEdges = 1600000;
static constexpr int kD     = 128;

// ---------------------------------------------------------------------------
// Phase 1: per-node partial dot products.
// h[n] = { emb[n]·W[0][0:128], emb[n]·W[1][0:128],
//          emb[n]·W[0][128:256], emb[n]·W[1][128:256] }
// 16 lanes per node, 8 columns per lane, W slices in registers.
// Memory-bound: reads 51.2 MB streaming, writes 1.6 MB.
// ---------------------------------------------------------------------------
__global__ __launch_bounds__(256) void node_pre(const float* __restrict__ emb,
                                                const float* __restrict__ W,
                                                float* __restrict__ h) {
    const int lane16 = threadIdx.x & 15;
    const int c0 = lane16 * 8;

    float w0[8], w1[8], w2[8], w3[8];
#pragma unroll
    for (int k = 0; k < 8; ++k) {
        w0[k] = W[c0 + k];            // W[0][c0+k]
        w1[k] = W[256 + c0 + k];      // W[1][c0+k]
        w2[k] = W[128 + c0 + k];      // W[0][128+c0+k]
        w3[k] = W[384 + c0 + k];      // W[1][128+c0+k]
    }

    const int n = (blockIdx.x * blockDim.x + threadIdx.x) >> 4;
    if (n >= kNodes) return;

    const float4* row = (const float4*)(emb + (size_t)n * kD + c0);
    float4 ea = row[0];
    float4 eb = row[1];
    float e[8] = {ea.x, ea.y, ea.z, ea.w, eb.x, eb.y, eb.z, eb.w};
    float p0 = 0.f, p1 = 0.f, p2 = 0.f, p3 = 0.f;
#pragma unroll
    for (int k = 0; k < 8; ++k) {
        p0 += e[k] * w0[k];
        p1 += e[k] * w1[k];
        p2 += e[k] * w2[k];
        p3 += e[k] * w3[k];
    }
    // reduce across the 16-lane group (xor masks 1,2,4,8 stay in-group)
#pragma unroll
    for (int m = 1; m < 16; m <<= 1) {
        p0 += __shfl_xor(p0, m, 64);
        p1 += __shfl_xor(p1, m, 64);
        p2 += __shfl_xor(p2, m, 64);
        p3 += __shfl_xor(p3, m, 64);
    }
    if (lane16 == 0) {
        ((float4*)h)[n] = make_float4(p0, p1, p2, p3);
    }
}

// ---------------------------------------------------------------------------
// Phase 2: 2 edges per thread. In-wave dtype detection (no extra kernel):
// every wave reads ei64[lane]; if any high word is nonzero the layout is
// int32 pairs (random indices < 100000 make all-zero impossible), else int64.
// Gathers 16B h-entries (1.6 MB table, L2-resident), 2-way softmax, float4 out.
// ---------------------------------------------------------------------------
__global__ __launch_bounds__(256) void edge_attn(const void* __restrict__ eiv,
                                                 const float* __restrict__ h,
                                                 const float* __restrict__ b,
                                                 float* __restrict__ out) {
    // wave-uniform layout detection: one coalesced 512B read (L2-hit after
    // the first block), ballot, branch.
    const unsigned long long* ei64 = (const unsigned long long*)eiv;
    unsigned long long hi = ei64[threadIdx.x & 63] >> 32;
    const bool is64 = (__ballot(hi != 0ull) == 0ull);

    const int e2 = blockIdx.x * blockDim.x + threadIdx.x;   // pair index
    if (e2 >= kEdges / 2) return;

    int r0, r1, c0, c1;
    if (is64) {
        ulonglong2 rr = ((const ulonglong2*)ei64)[e2];
        ulonglong2 cc = ((const ulonglong2*)(ei64 + kEdges))[e2];
        r0 = (int)rr.x; r1 = (int)rr.y;
        c0 = (int)cc.x; c1 = (int)cc.y;
    } else {
        const int* ei32 = (const int*)eiv;
        int2 rr = ((const int2*)ei32)[e2];
        int2 cc = ((const int2*)(ei32 + kEdges))[e2];
        r0 = rr.x; r1 = rr.y;
        c0 = cc.x; c1 = cc.y;
    }

    const float4* h4 = (const float4*)h;
    float4 hr0 = h4[r0];
    float4 hc0 = h4[c0];
    float4 hr1 = h4[r1];
    float4 hc1 = h4[c1];

    const float b0 = b[0], b1 = b[1];

    float s00 = hr0.x + hc0.z + b0;
    float s01 = hr0.y + hc0.w + b1;
    float m0  = fmaxf(s00, s01);
    float x00 = __expf(s00 - m0);
    float x01 = __expf(s01 - m0);
    float i0  = 1.0f / (x00 + x01);

    float s10 = hr1.x + hc1.z + b0;
    float s11 = hr1.y + hc1.w + b1;
    float m1  = fmaxf(s10, s11);
    float x10 = __expf(s10 - m1);
    float x11 = __expf(s11 - m1);
    float i1  = 1.0f / (x10 + x11);

    ((float4*)out)[e2] = make_float4(x00 * i0, x01 * i0, x10 * i1, x11 * i1);
}

extern "C" void kernel_launch(void* const* d_in, const int* in_sizes, int n_in,
                              void* d_out, int out_size, void* d_ws, size_t ws_size,
                              hipStream_t stream) {
    const float* emb = (const float*)d_in[0];
    const void*  ei  = d_in[1];
    const float* W   = (const float*)d_in[2];
    const float* b   = (const float*)d_in[3];
    float* out = (float*)d_out;

    float* h = (float*)d_ws;   // 1.6 MB node table, 16B-aligned

    // 16 lanes per node -> kNodes*16 threads
    node_pre<<<(kNodes * 16 + 255) / 256, 256, 0, stream>>>(emb, W, h);

    // 2 edges per thread
    edge_attn<<<(kEdges / 2 + 255) / 256, 256, 0, stream>>>(ei, h, b, out);
}